// Round 1
// baseline (139.664 us; speedup 1.0000x reference)
//
#include <hip/hip_runtime.h>
#include <hip/hip_bf16.h>

// OctreeConv: out[N,64] = sum_k gather_k(input)[N,32] @ W[k][32,64]
// N=262144, C_IN=32, C_OUT=64, K3=27. bf16 MFMA (16x16x32), fp32 accumulate.

typedef float f32x4 __attribute__((ext_vector_type(4)));
typedef __bf16 bf16x8 __attribute__((ext_vector_type(8)));

#define NN 262144
#define CI 32
#define CO 64
#define KK 27
#define WPAD 40              // 32 -> 40 bf16 (80B rows): 16B-aligned, bank-friendly
#define THREADS 1024
#define OCT_PER_BLOCK 256    // 16 waves x 16 octants

__device__ __forceinline__ ushort f2bf_rne(float f) {
  union { float f; unsigned u; } v; v.f = f;
  unsigned u = v.u;
  u += 0x7FFFu + ((u >> 16) & 1u);
  return (ushort)(u >> 16);
}

__global__ __launch_bounds__(THREADS, 1) void octconv_kernel(
    const float* __restrict__ input,    // [N][32]
    const float* __restrict__ weights,  // [27][32][64]
    const int*   __restrict__ neigh,    // [N][27]
    float*       __restrict__ out)      // [N][64]
{
  // Weights staged bf16, transposed to [k][o][c] (o-major) so a B fragment
  // (lane l: B[8*(l>>4)+j][l&15]) is one contiguous 16B ds_read_b128.
  __shared__ ushort w_lds[KK * CO * WPAD];   // 138,240 B

  const int tid = threadIdx.x;

  for (int i = tid; i < KK * CI * CO; i += THREADS) {
    const int k   = i >> 11;        // / (32*64)
    const int rem = i & 2047;
    const int c   = rem >> 6;       // / 64
    const int o   = rem & 63;
    w_lds[(k * CO + o) * WPAD + c] = f2bf_rne(weights[i]);
  }
  __syncthreads();

  const int wave = tid >> 6;
  const int lane = tid & 63;
  const int g    = lane >> 4;   // k-chunk / row-group selector
  const int r16  = lane & 15;   // A row within tile / B column
  const int oct_base = blockIdx.x * OCT_PER_BLOCK + wave * 16;
  const int row = oct_base + r16;

  // Preload this lane's neighbor row into registers (static-indexed via unroll)
  int nb[KK];
  const int* __restrict__ nrow = neigh + row * KK;
#pragma unroll
  for (int k = 0; k < KK; ++k) nb[k] = nrow[k];

  f32x4 acc0 = {0.f, 0.f, 0.f, 0.f};
  f32x4 acc1 = acc0, acc2 = acc0, acc3 = acc0;

#pragma unroll
  for (int k = 0; k < KK; ++k) {
    const int  idx   = nb[k];
    const bool valid = idx >= 0;
    const float* __restrict__ p =
        input + (size_t)(valid ? idx : 0) * CI + g * 8;
    f32x4 v0 = *(const f32x4*)p;
    f32x4 v1 = *(const f32x4*)(p + 4);
    if (!valid) {
      v0 = (f32x4){0.f, 0.f, 0.f, 0.f};
      v1 = (f32x4){0.f, 0.f, 0.f, 0.f};
    }
    bf16x8 a;
    a[0] = (__bf16)v0[0]; a[1] = (__bf16)v0[1];
    a[2] = (__bf16)v0[2]; a[3] = (__bf16)v0[3];
    a[4] = (__bf16)v1[0]; a[5] = (__bf16)v1[1];
    a[6] = (__bf16)v1[2]; a[7] = (__bf16)v1[3];

    const ushort* wk = &w_lds[(k * CO + r16) * WPAD + g * 8];
    bf16x8 b0 = *(const bf16x8*)(wk + 0 * 16 * WPAD);
    bf16x8 b1 = *(const bf16x8*)(wk + 1 * 16 * WPAD);
    bf16x8 b2 = *(const bf16x8*)(wk + 2 * 16 * WPAD);
    bf16x8 b3 = *(const bf16x8*)(wk + 3 * 16 * WPAD);

    acc0 = __builtin_amdgcn_mfma_f32_16x16x32_bf16(a, b0, acc0, 0, 0, 0);
    acc1 = __builtin_amdgcn_mfma_f32_16x16x32_bf16(a, b1, acc1, 0, 0, 0);
    acc2 = __builtin_amdgcn_mfma_f32_16x16x32_bf16(a, b2, acc2, 0, 0, 0);
    acc3 = __builtin_amdgcn_mfma_f32_16x16x32_bf16(a, b3, acc3, 0, 0, 0);
  }

  // C/D layout (m89-verified): col = lane&15, row = (lane>>4)*4 + reg
  float* __restrict__ obase = out + (size_t)(oct_base + g * 4) * CO + r16;
#pragma unroll
  for (int rr = 0; rr < 4; ++rr) {
    obase[rr * CO +  0] = acc0[rr];
    obase[rr * CO + 16] = acc1[rr];
    obase[rr * CO + 32] = acc2[rr];
    obase[rr * CO + 48] = acc3[rr];
  }
}

extern "C" void kernel_launch(void* const* d_in, const int* in_sizes, int n_in,
                              void* d_out, int out_size, void* d_ws, size_t ws_size,
                              hipStream_t stream) {
  const float* input   = (const float*)d_in[0];
  const float* weights = (const float*)d_in[1];
  const int*   neigh   = (const int*)d_in[2];
  float*       out     = (float*)d_out;

  dim3 grid(NN / OCT_PER_BLOCK);   // 1024 blocks
  octconv_kernel<<<grid, THREADS, 0, stream>>>(input, weights, neigh, out);
}